// Round 7
// baseline (156.308 us; speedup 1.0000x reference)
//
#include <hip/hip_runtime.h>
#include <hip/hip_bf16.h>
#include <stdint.h>

// Problem constants
#define N_ROWS 16384
#define C_ROWS 1000
#define C_PAD  1024
#define D_DIM  1024

#define BM 128
#define BN 128
#define BK 32

typedef __attribute__((ext_vector_type(8))) short    bf16x8;
typedef __attribute__((ext_vector_type(4))) float    f32x4;
typedef __attribute__((ext_vector_type(4))) uint32_t u32x4;

// fp32 -> bf16 truncation with round-half-up bias (cheap, error <= 2^-9 rel)
__device__ __forceinline__ uint32_t pk2bf(float lo, float hi) {
    union { float f; uint32_t u; } a, b;
    a.f = lo; b.f = hi;
    uint32_t l = (a.u + 0x8000u) >> 16;
    uint32_t h = (b.u + 0x8000u) >> 16;
    return l | (h << 16);
}

// One wave per row: sum of squares. Rows in [rows, pad_rows) get 0.
__global__ void row_norms_kernel(const float* __restrict__ x,
                                 float* __restrict__ out,
                                 int rows, int pad_rows) {
    int gid  = blockIdx.x * blockDim.x + threadIdx.x;
    int wid  = gid >> 6;
    int lane = threadIdx.x & 63;
    if (wid >= pad_rows) return;
    float s = 0.f;
    if (wid < rows) {
        const f32x4* rp = (const f32x4*)(x + (size_t)wid * D_DIM);
#pragma unroll
        for (int r = 0; r < D_DIM / 256; ++r) {   // 4 iters: lane reads 4 float4
            f32x4 v = rp[r * 64 + lane];
            s += v[0]*v[0] + v[1]*v[1] + v[2]*v[2] + v[3]*v[3];
        }
    }
#pragma unroll
    for (int off = 32; off > 0; off >>= 1) s += __shfl_down(s, off, 64);
    if (lane == 0) out[wid] = s;
}

// 128x128 tile, BK=32, 4 waves (2x2), 16x16x32 bf16 MFMA.
// A = E [16384 x 1024], B = centers [1000 x 1024] (both row-major = GEMM-BT).
// LDS slab-major layout: element (row, k) at ((k>>3)*128 + row)*8 + (k&7).
// -> staging ds_write_b128 and fragment ds_read_b128 are both contiguous
//    per 16-lane group => bank-conflict-free.
__global__ __launch_bounds__(256, 2)
void dist_gemm_kernel(const float* __restrict__ E,
                      const float* __restrict__ Cc,
                      const float* __restrict__ xn,
                      const float* __restrict__ yn,
                      float* __restrict__ out) {
    __shared__ uint16_t As[4 * 128 * 8];   // 8 KiB
    __shared__ uint16_t Bs[4 * 128 * 8];   // 8 KiB

    const int tid  = threadIdx.x;
    const int lane = tid & 63;
    const int wid  = tid >> 6;
    const int wm   = wid >> 1;            // 0..1
    const int wn   = wid & 1;             // 0..1

    const int rowTile = blockIdx.y;       // 0..127
    const int colTile = blockIdx.x;       // 0..7

    // staging assignment: thread -> (row 0..127, k-half 0/1 of the BK=32 step)
    const int srow = tid & 127;
    const int sp   = tid >> 7;            // 0/1 -> k offset sp*16 .. +15

    const int ga = rowTile * BM + srow;            // A row (always valid)
    const int gb = colTile * BN + srow;            // center row (may exceed 999)
    const float* Arow = E  + (size_t)ga * D_DIM + sp * 16;
    const float* Brow = Cc + (size_t)gb * D_DIM + sp * 16;
    const bool bvalid = (gb < C_ROWS);

    f32x4 acc[4][4];
#pragma unroll
    for (int m = 0; m < 4; ++m)
#pragma unroll
        for (int n = 0; n < 4; ++n)
            acc[m][n] = (f32x4)(0.f);

    // fragment base offsets (elements): slab=(lane>>4), row=wX*64+m*16+(lane&15)
    const int fragA_base = (((lane >> 4) * 128) + wm * 64 + (lane & 15)) * 8;
    const int fragB_base = (((lane >> 4) * 128) + wn * 64 + (lane & 15)) * 8;

    // staging LDS destinations (elements): cells (sp*2, srow) and (sp*2+1, srow)
    const int stA0 = ((sp * 2) * 128 + srow) * 8;
    const int stA1 = ((sp * 2 + 1) * 128 + srow) * 8;

    for (int k0 = 0; k0 < D_DIM; k0 += BK) {
        // ---- global load (fp32) ----
        f32x4 a0 = *(const f32x4*)(Arow + k0);
        f32x4 a1 = *(const f32x4*)(Arow + k0 + 4);
        f32x4 a2 = *(const f32x4*)(Arow + k0 + 8);
        f32x4 a3 = *(const f32x4*)(Arow + k0 + 12);
        f32x4 b0 = (f32x4)(0.f), b1 = (f32x4)(0.f),
              b2 = (f32x4)(0.f), b3 = (f32x4)(0.f);
        if (bvalid) {
            b0 = *(const f32x4*)(Brow + k0);
            b1 = *(const f32x4*)(Brow + k0 + 4);
            b2 = *(const f32x4*)(Brow + k0 + 8);
            b3 = *(const f32x4*)(Brow + k0 + 12);
        }
        // ---- convert to bf16 packed ----
        u32x4 pa01, pa23, pb01, pb23;
        pa01[0] = pk2bf(a0[0], a0[1]); pa01[1] = pk2bf(a0[2], a0[3]);
        pa01[2] = pk2bf(a1[0], a1[1]); pa01[3] = pk2bf(a1[2], a1[3]);
        pa23[0] = pk2bf(a2[0], a2[1]); pa23[1] = pk2bf(a2[2], a2[3]);
        pa23[2] = pk2bf(a3[0], a3[1]); pa23[3] = pk2bf(a3[2], a3[3]);
        pb01[0] = pk2bf(b0[0], b0[1]); pb01[1] = pk2bf(b0[2], b0[3]);
        pb01[2] = pk2bf(b1[0], b1[1]); pb01[3] = pk2bf(b1[2], b1[3]);
        pb23[0] = pk2bf(b2[0], b2[1]); pb23[1] = pk2bf(b2[2], b2[3]);
        pb23[2] = pk2bf(b3[0], b3[1]); pb23[3] = pk2bf(b3[2], b3[3]);

        __syncthreads();   // previous iteration's reads done
        *(u32x4*)&As[stA0] = pa01;
        *(u32x4*)&As[stA1] = pa23;
        *(u32x4*)&Bs[stA0] = pb01;
        *(u32x4*)&Bs[stA1] = pb23;
        __syncthreads();   // staged data visible

        // ---- compute: 8 ds_read_b128 + 16 MFMA ----
        bf16x8 ar[4], br[4];
#pragma unroll
        for (int m = 0; m < 4; ++m)
            ar[m] = *(const bf16x8*)&As[fragA_base + m * 16 * 8];
#pragma unroll
        for (int n = 0; n < 4; ++n)
            br[n] = *(const bf16x8*)&Bs[fragB_base + n * 16 * 8];
#pragma unroll
        for (int m = 0; m < 4; ++m)
#pragma unroll
            for (int n = 0; n < 4; ++n)
                acc[m][n] = __builtin_amdgcn_mfma_f32_16x16x32_bf16(
                    ar[m], br[n], acc[m][n], 0, 0, 0);
    }

    // ---- epilogue: out = max(xn + yn - 2*dot, 0), col-bounds for N=1000 ----
    const int orow0 = rowTile * BM + wm * 64 + ((lane >> 4) * 4);
    const int ocol0 = colTile * BN + wn * 64 + (lane & 15);
#pragma unroll
    for (int n = 0; n < 4; ++n) {
        int gc = ocol0 + n * 16;
        if (gc >= C_ROWS) continue;
        float ynv = yn[gc];
#pragma unroll
        for (int m = 0; m < 4; ++m) {
            int gr = orow0 + m * 16;
#pragma unroll
            for (int r = 0; r < 4; ++r) {
                float v = xn[gr + r] + ynv - 2.0f * acc[m][n][r];
                out[(size_t)(gr + r) * C_ROWS + gc] = fmaxf(v, 0.f);
            }
        }
    }
}

extern "C" void kernel_launch(void* const* d_in, const int* in_sizes, int n_in,
                              void* d_out, int out_size, void* d_ws, size_t ws_size,
                              hipStream_t stream) {
    const float* E  = (const float*)d_in[0];   // [16384, 1024]
    const float* Cc = (const float*)d_in[1];   // [1000, 1024]
    float* out = (float*)d_out;                // [16384, 1000]

    float* xn = (float*)d_ws;                  // 16384 floats
    float* yn = xn + N_ROWS;                   // 1024 floats (padded)

    // norms (also pre-warms E into L3 for the GEMM)
    row_norms_kernel<<<N_ROWS / 4, 256, 0, stream>>>(E, xn, N_ROWS, N_ROWS);
    row_norms_kernel<<<C_PAD / 4, 256, 0, stream>>>(Cc, yn, C_ROWS, C_PAD);

    dim3 grid(C_PAD / BN, N_ROWS / BM);        // (8, 128)
    dist_gemm_kernel<<<grid, 256, 0, stream>>>(E, Cc, xn, yn, out);
}

// Round 8
// 102.488 us; speedup vs baseline: 1.5251x; 1.5251x over previous
//
#include <hip/hip_runtime.h>
#include <hip/hip_bf16.h>
#include <stdint.h>

// Problem constants
#define N_ROWS 16384
#define C_ROWS 1000
#define C_PAD  1024
#define D_DIM  1024

#define BM 128
#define BN 128
#define BK 32
#define KSTEPS (D_DIM / BK)   // 32

typedef __attribute__((ext_vector_type(8))) short    bf16x8;
typedef __attribute__((ext_vector_type(4))) float    f32x4;
typedef __attribute__((ext_vector_type(4))) uint32_t u32x4;

// fp32 -> bf16 with round-half-up bias (same rounding as validated round-7 kernel)
__device__ __forceinline__ uint32_t pk2bf(float lo, float hi) {
    union { float f; uint32_t u; } a, b;
    a.f = lo; b.f = hi;
    uint32_t l = (a.u + 0x8000u) >> 16;
    uint32_t h = (b.u + 0x8000u) >> 16;
    return l | (h << 16);
}

// async global->LDS, 16 bytes per lane. LDS dest = uniform base + lane*16 (HW).
__device__ __forceinline__ void gl_lds16(const uint16_t* g, uint16_t* l) {
    __builtin_amdgcn_global_load_lds(
        (const __attribute__((address_space(1))) void*)g,
        (__attribute__((address_space(3))) void*)l,
        16, 0, 0);
}

// ---------------- pre-pass: fused fp32->bf16 convert + row sq-norm ----------
// one wave per row; rows in [rows, pad_rows) get zeros.
__global__ void convert_norm_kernel(const float* __restrict__ x,
                                    uint16_t* __restrict__ xb,
                                    float* __restrict__ norms,
                                    int rows, int pad_rows) {
    int wid  = (blockIdx.x * blockDim.x + threadIdx.x) >> 6;
    int lane = threadIdx.x & 63;
    if (wid >= pad_rows) return;
    ushort4* wp = (ushort4*)(xb + (size_t)wid * D_DIM);
    if (wid < rows) {
        const f32x4* rp = (const f32x4*)(x + (size_t)wid * D_DIM);
        float s = 0.f;
#pragma unroll
        for (int r = 0; r < 4; ++r) {           // 4 x (float4 per lane) = 1024
            f32x4 v = rp[r * 64 + lane];
            s += v[0]*v[0] + v[1]*v[1] + v[2]*v[2] + v[3]*v[3];
            uint32_t p0 = pk2bf(v[0], v[1]);
            uint32_t p1 = pk2bf(v[2], v[3]);
            ushort4 w;
            w.x = (unsigned short)(p0 & 0xffff); w.y = (unsigned short)(p0 >> 16);
            w.z = (unsigned short)(p1 & 0xffff); w.w = (unsigned short)(p1 >> 16);
            wp[r * 64 + lane] = w;
        }
#pragma unroll
        for (int off = 32; off > 0; off >>= 1) s += __shfl_down(s, off, 64);
        if (lane == 0) norms[wid] = s;
    } else {
        ushort4 z = {0, 0, 0, 0};
#pragma unroll
        for (int r = 0; r < 4; ++r) wp[r * 64 + lane] = z;
        if (lane == 0) norms[wid] = 0.f;
    }
}

// ---------------- main GEMM: 128x128 tile, BK=32, double-buffered gload_lds --
// LDS slab-major: cell (row, kslot) at elem ((kslot)*128 + row)*8, kslot=k/8.
// staging: wave w call j covers cells [w*64 + j*256, +64) -> one slab, rows
// r0..r0+63; per-lane GLOBAL addr carries the layout, LDS dest is linear.
// frag ds_read: lanes 0..15 read consecutive cells -> conflict-free (verified
// round 7: SQ_LDS_BANK_CONFLICT == 0).
__global__ __launch_bounds__(256, 4)
void dist_gemm2(const uint16_t* __restrict__ Ab,
                const uint16_t* __restrict__ Bb,
                const float* __restrict__ xn,
                const float* __restrict__ yn,
                float* __restrict__ out) {
    __shared__ uint16_t As[2][BM * BK];   // 2 x 8 KiB
    __shared__ uint16_t Bs[2][BM * BK];   // 2 x 8 KiB

    const int tid  = threadIdx.x;
    const int lane = tid & 63;
    const int wid  = tid >> 6;
    const int wm   = wid >> 1;
    const int wn   = wid & 1;

    const int rowTile = blockIdx.x;   // 0..127  (bid%8 == rowTile%8 -> XCD reuse)
    const int colTile = blockIdx.y;   // 0..7

    // staging geometry
    const int slab0 = wid >> 1;              // call0 slab (0..1), call1 = +2
    const int r0    = (wid & 1) * 64;        // row base within tile
    const int arow  = rowTile * BM + r0 + lane;
    const int brow  = colTile * BN + r0 + lane;
    const size_t aoff0 = (size_t)arow * D_DIM + slab0 * 8;   // elements
    const size_t boff0 = (size_t)brow * D_DIM + slab0 * 8;
    const int ldsc0 = (wid * 64) * 8;        // cellbase*8 elems (call 0)
    const int ldsc1 = (wid * 64 + 256) * 8;  // call 1 (+2 slabs)

    // fragment read offsets (elements)
    const int fA = ((lane >> 4) * 128 + wm * 64 + (lane & 15)) * 8;
    const int fB = ((lane >> 4) * 128 + wn * 64 + (lane & 15)) * 8;

    f32x4 acc[4][4];
#pragma unroll
    for (int m = 0; m < 4; ++m)
#pragma unroll
        for (int n = 0; n < 4; ++n) acc[m][n] = (f32x4)(0.f);

#define STAGE(buf, k0)                                              \
    do {                                                            \
        gl_lds16(Ab + aoff0 + (k0),      &As[buf][ldsc0]);          \
        gl_lds16(Ab + aoff0 + (k0) + 16, &As[buf][ldsc1]);          \
        gl_lds16(Bb + boff0 + (k0),      &Bs[buf][ldsc0]);          \
        gl_lds16(Bb + boff0 + (k0) + 16, &Bs[buf][ldsc1]);          \
    } while (0)

    STAGE(0, 0);
    __syncthreads();                       // drain vmcnt, buf0 ready

    int cur = 0;
    for (int t = 0; t < KSTEPS; ++t) {
        if (t + 1 < KSTEPS) STAGE(cur ^ 1, (t + 1) * BK);   // prefetch next
        bf16x8 ar[4], br[4];
#pragma unroll
        for (int m = 0; m < 4; ++m) ar[m] = *(const bf16x8*)&As[cur][fA + m * 16 * 8];
#pragma unroll
        for (int n = 0; n < 4; ++n) br[n] = *(const bf16x8*)&Bs[cur][fB + n * 16 * 8];
#pragma unroll
        for (int m = 0; m < 4; ++m)
#pragma unroll
            for (int n = 0; n < 4; ++n)
                acc[m][n] = __builtin_amdgcn_mfma_f32_16x16x32_bf16(
                    ar[m], br[n], acc[m][n], 0, 0, 0);
        __syncthreads();                   // next buf loaded; reads of cur done
        cur ^= 1;
    }
#undef STAGE

    // epilogue: out = max(xn + yn - 2*dot, 0), col bound-check for N=1000
    const int orow0 = rowTile * BM + wm * 64 + ((lane >> 4) * 4);
    const int ocol0 = colTile * BN + wn * 64 + (lane & 15);
#pragma unroll
    for (int n = 0; n < 4; ++n) {
        int gc = ocol0 + n * 16;
        if (gc >= C_ROWS) continue;
        float ynv = yn[gc];
#pragma unroll
        for (int m = 0; m < 4; ++m) {
            int gr = orow0 + m * 16;
#pragma unroll
            for (int r = 0; r < 4; ++r) {
                float v = xn[gr + r] + ynv - 2.0f * acc[m][n][r];
                out[(size_t)(gr + r) * C_ROWS + gc] = fmaxf(v, 0.f);
            }
        }
    }
}

// ---------------- fallback path (round-7 validated) if ws is too small ------
__global__ void row_norms_kernel(const float* __restrict__ x,
                                 float* __restrict__ out,
                                 int rows, int pad_rows) {
    int gid  = blockIdx.x * blockDim.x + threadIdx.x;
    int wid  = gid >> 6;
    int lane = threadIdx.x & 63;
    if (wid >= pad_rows) return;
    float s = 0.f;
    if (wid < rows) {
        const f32x4* rp = (const f32x4*)(x + (size_t)wid * D_DIM);
#pragma unroll
        for (int r = 0; r < D_DIM / 256; ++r) {
            f32x4 v = rp[r * 64 + lane];
            s += v[0]*v[0] + v[1]*v[1] + v[2]*v[2] + v[3]*v[3];
        }
    }
#pragma unroll
    for (int off = 32; off > 0; off >>= 1) s += __shfl_down(s, off, 64);
    if (lane == 0) out[wid] = s;
}

__global__ __launch_bounds__(256, 2)
void dist_gemm_kernel(const float* __restrict__ E,
                      const float* __restrict__ Cc,
                      const float* __restrict__ xn,
                      const float* __restrict__ yn,
                      float* __restrict__ out) {
    __shared__ uint16_t As[4 * 128 * 8];
    __shared__ uint16_t Bs[4 * 128 * 8];
    const int tid  = threadIdx.x;
    const int lane = tid & 63;
    const int wid  = tid >> 6;
    const int wm   = wid >> 1;
    const int wn   = wid & 1;
    const int rowTile = blockIdx.y;
    const int colTile = blockIdx.x;
    const int srow = tid & 127;
    const int sp   = tid >> 7;
    const int ga = rowTile * BM + srow;
    const int gb = colTile * BN + srow;
    const float* Arow = E  + (size_t)ga * D_DIM + sp * 16;
    const float* Brow = Cc + (size_t)gb * D_DIM + sp * 16;
    const bool bvalid = (gb < C_ROWS);
    f32x4 acc[4][4];
#pragma unroll
    for (int m = 0; m < 4; ++m)
#pragma unroll
        for (int n = 0; n < 4; ++n) acc[m][n] = (f32x4)(0.f);
    const int fragA_base = (((lane >> 4) * 128) + wm * 64 + (lane & 15)) * 8;
    const int fragB_base = (((lane >> 4) * 128) + wn * 64 + (lane & 15)) * 8;
    const int stA0 = ((sp * 2) * 128 + srow) * 8;
    const int stA1 = ((sp * 2 + 1) * 128 + srow) * 8;
    for (int k0 = 0; k0 < D_DIM; k0 += BK) {
        f32x4 a0 = *(const f32x4*)(Arow + k0);
        f32x4 a1 = *(const f32x4*)(Arow + k0 + 4);
        f32x4 a2 = *(const f32x4*)(Arow + k0 + 8);
        f32x4 a3 = *(const f32x4*)(Arow + k0 + 12);
        f32x4 b0 = (f32x4)(0.f), b1 = (f32x4)(0.f),
              b2 = (f32x4)(0.f), b3 = (f32x4)(0.f);
        if (bvalid) {
            b0 = *(const f32x4*)(Brow + k0);
            b1 = *(const f32x4*)(Brow + k0 + 4);
            b2 = *(const f32x4*)(Brow + k0 + 8);
            b3 = *(const f32x4*)(Brow + k0 + 12);
        }
        u32x4 pa01, pa23, pb01, pb23;
        pa01[0] = pk2bf(a0[0], a0[1]); pa01[1] = pk2bf(a0[2], a0[3]);
        pa01[2] = pk2bf(a1[0], a1[1]); pa01[3] = pk2bf(a1[2], a1[3]);
        pa23[0] = pk2bf(a2[0], a2[1]); pa23[1] = pk2bf(a2[2], a2[3]);
        pa23[2] = pk2bf(a3[0], a3[1]); pa23[3] = pk2bf(a3[2], a3[3]);
        pb01[0] = pk2bf(b0[0], b0[1]); pb01[1] = pk2bf(b0[2], b0[3]);
        pb01[2] = pk2bf(b1[0], b1[1]); pb01[3] = pk2bf(b1[2], b1[3]);
        pb23[0] = pk2bf(b2[0], b2[1]); pb23[1] = pk2bf(b2[2], b2[3]);
        pb23[2] = pk2bf(b3[0], b3[1]); pb23[3] = pk2bf(b3[2], b3[3]);
        __syncthreads();
        *(u32x4*)&As[stA0] = pa01;
        *(u32x4*)&As[stA1] = pa23;
        *(u32x4*)&Bs[stA0] = pb01;
        *(u32x4*)&Bs[stA1] = pb23;
        __syncthreads();
        bf16x8 ar[4], br[4];
#pragma unroll
        for (int m = 0; m < 4; ++m) ar[m] = *(const bf16x8*)&As[fragA_base + m * 16 * 8];
#pragma unroll
        for (int n = 0; n < 4; ++n) br[n] = *(const bf16x8*)&Bs[fragB_base + n * 16 * 8];
#pragma unroll
        for (int m = 0; m < 4; ++m)
#pragma unroll
            for (int n = 0; n < 4; ++n)
                acc[m][n] = __builtin_amdgcn_mfma_f32_16x16x32_bf16(
                    ar[m], br[n], acc[m][n], 0, 0, 0);
    }
    const int orow0 = rowTile * BM + wm * 64 + ((lane >> 4) * 4);
    const int ocol0 = colTile * BN + wn * 64 + (lane & 15);
#pragma unroll
    for (int n = 0; n < 4; ++n) {
        int gc = ocol0 + n * 16;
        if (gc >= C_ROWS) continue;
        float ynv = yn[gc];
#pragma unroll
        for (int m = 0; m < 4; ++m) {
            int gr = orow0 + m * 16;
#pragma unroll
            for (int r = 0; r < 4; ++r) {
                float v = xn[gr + r] + ynv - 2.0f * acc[m][n][r];
                out[(size_t)(gr + r) * C_ROWS + gc] = fmaxf(v, 0.f);
            }
        }
    }
}

extern "C" void kernel_launch(void* const* d_in, const int* in_sizes, int n_in,
                              void* d_out, int out_size, void* d_ws, size_t ws_size,
                              hipStream_t stream) {
    const float* E  = (const float*)d_in[0];   // [16384, 1024]
    const float* Cc = (const float*)d_in[1];   // [1000, 1024]
    float* out = (float*)d_out;                // [16384, 1000]

    // ws layout (new path): Ebf 32MB | Cbf 2MB | xn 64KB | yn 4KB
    uint16_t* Ebf = (uint16_t*)d_ws;
    uint16_t* Cbf = Ebf + (size_t)N_ROWS * D_DIM;
    float*    xn  = (float*)(Cbf + (size_t)C_PAD * D_DIM);
    float*    yn  = xn + N_ROWS;
    size_t need = (size_t)((char*)(yn + C_PAD) - (char*)d_ws);

    if (ws_size >= need) {
        convert_norm_kernel<<<N_ROWS / 4, 256, 0, stream>>>(E,  Ebf, xn, N_ROWS, N_ROWS);
        convert_norm_kernel<<<C_PAD  / 4, 256, 0, stream>>>(Cc, Cbf, yn, C_ROWS, C_PAD);
        dim3 grid(N_ROWS / BM, C_PAD / BN);    // (128, 8): bid%8==rowTile%8
        dist_gemm2<<<grid, 256, 0, stream>>>(Ebf, Cbf, xn, yn, out);
    } else {
        // fallback: round-7 validated path (needs only ~68 KB ws)
        float* fxn = (float*)d_ws;
        float* fyn = fxn + N_ROWS;
        row_norms_kernel<<<N_ROWS / 4, 256, 0, stream>>>(E,  fxn, N_ROWS, N_ROWS);
        row_norms_kernel<<<C_PAD  / 4, 256, 0, stream>>>(Cc, fyn, C_ROWS, C_PAD);
        dim3 grid(C_PAD / BN, N_ROWS / BM);
        dist_gemm_kernel<<<grid, 256, 0, stream>>>(E, Cc, fxn, fyn, out);
    }
}

// Round 10
// 71.245 us; speedup vs baseline: 2.1940x; 1.4385x over previous
//
#include <hip/hip_runtime.h>
#include <hip/hip_bf16.h>
#include <stdint.h>

// Problem constants
#define N_ROWS 16384
#define C_ROWS 1000
#define C_PAD  1024
#define D_DIM  1024

#define BM 128
#define BN 128
#define BK 32
#define KSTEPS (D_DIM / BK)        // 32
#define TILE_ELEMS (BM * BK)       // 4096 elems = 8 KiB per K-step image

typedef __attribute__((ext_vector_type(8))) short    bf16x8;
typedef __attribute__((ext_vector_type(4))) float    f32x4;
typedef __attribute__((ext_vector_type(4))) uint32_t u32x4;

// fp32 -> bf16 with round-half-up bias (validated: absmax 16.0 vs thr 50.88)
__device__ __forceinline__ uint32_t pk2bf(float lo, float hi) {
    union { float f; uint32_t u; } a, b;
    a.f = lo; b.f = hi;
    uint32_t l = (a.u + 0x8000u) >> 16;
    uint32_t h = (b.u + 0x8000u) >> 16;
    return l | (h << 16);
}

// async global->LDS, 16 bytes per lane. LDS dest = uniform base + lane*16 (HW).
__device__ __forceinline__ void gl_lds16(const uint16_t* g, uint16_t* l) {
    __builtin_amdgcn_global_load_lds(
        (const __attribute__((address_space(1))) void*)g,
        (__attribute__((address_space(3))) void*)l,
        16, 0, 0);
}

// ---------------- pre-pass: fp32 -> bf16 TILED convert + row sq-norm --------
// Tiled layout = the exact LDS image the GEMM stages:
//   elem (r, k) -> [(r/128)*KSTEPS + k/32]*4096 + ((k%32)/8)*128*8 + (r%128)*8 + k%8
// One wave per row; 2 iterations x (8 elems/lane). Rows >= `rows` get zeros.
__global__ void convert_norm_tiled(const float* __restrict__ x,
                                   uint16_t* __restrict__ xt,
                                   float* __restrict__ norms,
                                   int rows, int pad_rows) {
    int wid  = (blockIdx.x * blockDim.x + threadIdx.x) >> 6;
    int lane = threadIdx.x & 63;
    if (wid >= pad_rows) return;
    const int tile = wid >> 7;
    const int row  = wid & 127;
    uint16_t* tbase = xt + (size_t)tile * KSTEPS * TILE_ELEMS;
    const int kslot = lane & 3;                 // (k%32)/8
    const int cellb = (kslot * 128 + row) * 8;  // elems within the 4096 image
    if (wid < rows) {
        const f32x4* rp = (const f32x4*)(x + (size_t)wid * D_DIM);
        float s = 0.f;
#pragma unroll
        for (int i = 0; i < 2; ++i) {           // k = i*512 + lane*8 .. +7
            f32x4 v0 = rp[i * 128 + lane * 2];
            f32x4 v1 = rp[i * 128 + lane * 2 + 1];
            s += v0[0]*v0[0] + v0[1]*v0[1] + v0[2]*v0[2] + v0[3]*v0[3]
               + v1[0]*v1[0] + v1[1]*v1[1] + v1[2]*v1[2] + v1[3]*v1[3];
            u32x4 p;
            p[0] = pk2bf(v0[0], v0[1]); p[1] = pk2bf(v0[2], v0[3]);
            p[2] = pk2bf(v1[0], v1[1]); p[3] = pk2bf(v1[2], v1[3]);
            const int t = i * 16 + (lane >> 2); // k/32
            *(u32x4*)(tbase + (size_t)t * TILE_ELEMS + cellb) = p;
        }
#pragma unroll
        for (int off = 32; off > 0; off >>= 1) s += __shfl_down(s, off, 64);
        if (lane == 0) norms[wid] = s;
    } else {
        u32x4 z = {0, 0, 0, 0};
#pragma unroll
        for (int i = 0; i < 2; ++i) {
            const int t = i * 16 + (lane >> 2);
            *(u32x4*)(tbase + (size_t)t * TILE_ELEMS + cellb) = z;
        }
        if (lane == 0) norms[wid] = 0.f;
    }
}

// ---------------- main GEMM: 128x128, BK=32, dbuf, COALESCED gload_lds ------
// Source is pre-tiled -> staging is linear: global offset == LDS offset ==
// tid*16B (+2KB for call 1). 1KB contiguous per instruction per wave.
// Fragment ds_read layout identical to round-8 (SQ_LDS_BANK_CONFLICT == 0).
__global__ __launch_bounds__(256, 4)
void dist_gemm2(const uint16_t* __restrict__ At,
                const uint16_t* __restrict__ Bt,
                const float* __restrict__ xn,
                const float* __restrict__ yn,
                float* __restrict__ out) {
    __shared__ uint16_t As[2][TILE_ELEMS];   // 2 x 8 KiB
    __shared__ uint16_t Bs[2][TILE_ELEMS];   // 2 x 8 KiB

    const int tid  = threadIdx.x;
    const int lane = tid & 63;
    const int wid  = tid >> 6;
    const int wm   = wid >> 1;
    const int wn   = wid & 1;

    const int rowTile = blockIdx.x;   // 0..127 ; bid = rowTile + 128*colTile
    const int colTile = blockIdx.y;   // 0..7   ; -> same rowTile => same XCD

    const uint16_t* Abase = At + (size_t)rowTile * KSTEPS * TILE_ELEMS;
    const uint16_t* Bbase = Bt + (size_t)colTile * KSTEPS * TILE_ELEMS;

    const int off0 = tid * 8;          // elems (16B per thread)
    const int off1 = 2048 + tid * 8;   // second 4KB half

    // fragment read offsets (elements)
    const int fA = ((lane >> 4) * 128 + wm * 64 + (lane & 15)) * 8;
    const int fB = ((lane >> 4) * 128 + wn * 64 + (lane & 15)) * 8;

    f32x4 acc[4][4];
#pragma unroll
    for (int m = 0; m < 4; ++m)
#pragma unroll
        for (int n = 0; n < 4; ++n) acc[m][n] = (f32x4)(0.f);

#define STAGE(buf, t)                                               \
    do {                                                            \
        const uint16_t* ga = Abase + (size_t)(t) * TILE_ELEMS;      \
        const uint16_t* gb = Bbase + (size_t)(t) * TILE_ELEMS;      \
        gl_lds16(ga + off0, &As[buf][off0]);                        \
        gl_lds16(ga + off1, &As[buf][off1]);                        \
        gl_lds16(gb + off0, &Bs[buf][off0]);                        \
        gl_lds16(gb + off1, &Bs[buf][off1]);                        \
    } while (0)

    STAGE(0, 0);
    __syncthreads();                       // vmcnt drained, buf0 ready

    int cur = 0;
    for (int t = 0; t < KSTEPS; ++t) {
        if (t + 1 < KSTEPS) STAGE(cur ^ 1, t + 1);   // prefetch next tile
        bf16x8 ar[4], br[4];
#pragma unroll
        for (int m = 0; m < 4; ++m) ar[m] = *(const bf16x8*)&As[cur][fA + m * 16 * 8];
#pragma unroll
        for (int n = 0; n < 4; ++n) br[n] = *(const bf16x8*)&Bs[cur][fB + n * 16 * 8];
#pragma unroll
        for (int m = 0; m < 4; ++m)
#pragma unroll
            for (int n = 0; n < 4; ++n)
                acc[m][n] = __builtin_amdgcn_mfma_f32_16x16x32_bf16(
                    ar[m], br[n], acc[m][n], 0, 0, 0);
        __syncthreads();                   // next buf loaded; reads of cur done
        cur ^= 1;
    }
#undef STAGE

    // epilogue: out = max(xn + yn - 2*dot, 0), col bound-check for N=1000
    const int orow0 = rowTile * BM + wm * 64 + ((lane >> 4) * 4);
    const int ocol0 = colTile * BN + wn * 64 + (lane & 15);
#pragma unroll
    for (int n = 0; n < 4; ++n) {
        int gc = ocol0 + n * 16;
        if (gc >= C_ROWS) continue;
        float ynv = yn[gc];
#pragma unroll
        for (int m = 0; m < 4; ++m) {
            int gr = orow0 + m * 16;
#pragma unroll
            for (int r = 0; r < 4; ++r) {
                float v = xn[gr + r] + ynv - 2.0f * acc[m][n][r];
                out[(size_t)(gr + r) * C_ROWS + gc] = fmaxf(v, 0.f);
            }
        }
    }
}

// ---------------- fallback path (round-7 validated) if ws is too small ------
__global__ void row_norms_kernel(const float* __restrict__ x,
                                 float* __restrict__ out,
                                 int rows, int pad_rows) {
    int gid  = blockIdx.x * blockDim.x + threadIdx.x;
    int wid  = gid >> 6;
    int lane = threadIdx.x & 63;
    if (wid >= pad_rows) return;
    float s = 0.f;
    if (wid < rows) {
        const f32x4* rp = (const f32x4*)(x + (size_t)wid * D_DIM);
#pragma unroll
        for (int r = 0; r < D_DIM / 256; ++r) {
            f32x4 v = rp[r * 64 + lane];
            s += v[0]*v[0] + v[1]*v[1] + v[2]*v[2] + v[3]*v[3];
        }
    }
#pragma unroll
    for (int off = 32; off > 0; off >>= 1) s += __shfl_down(s, off, 64);
    if (lane == 0) out[wid] = s;
}

__global__ __launch_bounds__(256, 2)
void dist_gemm_kernel(const float* __restrict__ E,
                      const float* __restrict__ Cc,
                      const float* __restrict__ xn,
                      const float* __restrict__ yn,
                      float* __restrict__ out) {
    __shared__ uint16_t As[4 * 128 * 8];
    __shared__ uint16_t Bs[4 * 128 * 8];
    const int tid  = threadIdx.x;
    const int lane = tid & 63;
    const int wid  = tid >> 6;
    const int wm   = wid >> 1;
    const int wn   = wid & 1;
    const int rowTile = blockIdx.y;
    const int colTile = blockIdx.x;
    const int srow = tid & 127;
    const int sp   = tid >> 7;
    const int ga = rowTile * BM + srow;
    const int gb = colTile * BN + srow;
    const float* Arow = E  + (size_t)ga * D_DIM + sp * 16;
    const float* Brow = Cc + (size_t)gb * D_DIM + sp * 16;
    const bool bvalid = (gb < C_ROWS);
    f32x4 acc[4][4];
#pragma unroll
    for (int m = 0; m < 4; ++m)
#pragma unroll
        for (int n = 0; n < 4; ++n) acc[m][n] = (f32x4)(0.f);
    const int fragA_base = (((lane >> 4) * 128) + wm * 64 + (lane & 15)) * 8;
    const int fragB_base = (((lane >> 4) * 128) + wn * 64 + (lane & 15)) * 8;
    const int stA0 = ((sp * 2) * 128 + srow) * 8;
    const int stA1 = ((sp * 2 + 1) * 128 + srow) * 8;
    for (int k0 = 0; k0 < D_DIM; k0 += BK) {
        f32x4 a0 = *(const f32x4*)(Arow + k0);
        f32x4 a1 = *(const f32x4*)(Arow + k0 + 4);
        f32x4 a2 = *(const f32x4*)(Arow + k0 + 8);
        f32x4 a3 = *(const f32x4*)(Arow + k0 + 12);
        f32x4 b0 = (f32x4)(0.f), b1 = (f32x4)(0.f),
              b2 = (f32x4)(0.f), b3 = (f32x4)(0.f);
        if (bvalid) {
            b0 = *(const f32x4*)(Brow + k0);
            b1 = *(const f32x4*)(Brow + k0 + 4);
            b2 = *(const f32x4*)(Brow + k0 + 8);
            b3 = *(const f32x4*)(Brow + k0 + 12);
        }
        u32x4 pa01, pa23, pb01, pb23;
        pa01[0] = pk2bf(a0[0], a0[1]); pa01[1] = pk2bf(a0[2], a0[3]);
        pa01[2] = pk2bf(a1[0], a1[1]); pa01[3] = pk2bf(a1[2], a1[3]);
        pa23[0] = pk2bf(a2[0], a2[1]); pa23[1] = pk2bf(a2[2], a2[3]);
        pa23[2] = pk2bf(a3[0], a3[1]); pa23[3] = pk2bf(a3[2], a3[3]);
        pb01[0] = pk2bf(b0[0], b0[1]); pb01[1] = pk2bf(b0[2], b0[3]);
        pb01[2] = pk2bf(b1[0], b1[1]); pb01[3] = pk2bf(b1[2], b1[3]);
        pb23[0] = pk2bf(b2[0], b2[1]); pb23[1] = pk2bf(b2[2], b2[3]);
        pb23[2] = pk2bf(b3[0], b3[1]); pb23[3] = pk2bf(b3[2], b3[3]);
        __syncthreads();
        *(u32x4*)&As[stA0] = pa01;
        *(u32x4*)&As[stA1] = pa23;
        *(u32x4*)&Bs[stA0] = pb01;
        *(u32x4*)&Bs[stA1] = pb23;
        __syncthreads();
        bf16x8 ar[4], br[4];
#pragma unroll
        for (int m = 0; m < 4; ++m) ar[m] = *(const bf16x8*)&As[fragA_base + m * 16 * 8];
#pragma unroll
        for (int n = 0; n < 4; ++n) br[n] = *(const bf16x8*)&Bs[fragB_base + n * 16 * 8];
#pragma unroll
        for (int m = 0; m < 4; ++m)
#pragma unroll
            for (int n = 0; n < 4; ++n)
                acc[m][n] = __builtin_amdgcn_mfma_f32_16x16x32_bf16(
                    ar[m], br[n], acc[m][n], 0, 0, 0);
    }
    const int orow0 = rowTile * BM + wm * 64 + ((lane >> 4) * 4);
    const int ocol0 = colTile * BN + wn * 64 + (lane & 15);
#pragma unroll
    for (int n = 0; n < 4; ++n) {
        int gc = ocol0 + n * 16;
        if (gc >= C_ROWS) continue;
        float ynv = yn[gc];
#pragma unroll
        for (int m = 0; m < 4; ++m) {
            int gr = orow0 + m * 16;
#pragma unroll
            for (int r = 0; r < 4; ++r) {
                float v = xn[gr + r] + ynv - 2.0f * acc[m][n][r];
                out[(size_t)(gr + r) * C_ROWS + gc] = fmaxf(v, 0.f);
            }
        }
    }
}

extern "C" void kernel_launch(void* const* d_in, const int* in_sizes, int n_in,
                              void* d_out, int out_size, void* d_ws, size_t ws_size,
                              hipStream_t stream) {
    const float* E  = (const float*)d_in[0];   // [16384, 1024]
    const float* Cc = (const float*)d_in[1];   // [1000, 1024]
    float* out = (float*)d_out;                // [16384, 1000]

    // ws layout: Et 32MB | Ct 2MB | xn 64KB | yn 4KB  (tiled bf16 images)
    uint16_t* Et = (uint16_t*)d_ws;
    uint16_t* Ct = Et + (size_t)N_ROWS * D_DIM;
    float*    xn = (float*)(Ct + (size_t)C_PAD * D_DIM);
    float*    yn = xn + N_ROWS;
    size_t need = (size_t)((char*)(yn + C_PAD) - (char*)d_ws);

    if (ws_size >= need) {
        convert_norm_tiled<<<N_ROWS / 4, 256, 0, stream>>>(E,  Et, xn, N_ROWS, N_ROWS);
        convert_norm_tiled<<<C_PAD  / 4, 256, 0, stream>>>(Cc, Ct, yn, C_ROWS, C_PAD);
        dim3 grid(N_ROWS / BM, C_PAD / BN);    // (128, 8)
        dist_gemm2<<<grid, 256, 0, stream>>>(Et, Ct, xn, yn, out);
    } else {
        // fallback: round-7 validated path (needs only ~68 KB ws)
        float* fxn = (float*)d_ws;
        float* fyn = fxn + N_ROWS;
        row_norms_kernel<<<N_ROWS / 4, 256, 0, stream>>>(E,  fxn, N_ROWS, N_ROWS);
        row_norms_kernel<<<C_PAD  / 4, 256, 0, stream>>>(Cc, fyn, C_ROWS, C_PAD);
        dim3 grid(C_PAD / BN, N_ROWS / BM);
        dist_gemm_kernel<<<grid, 256, 0, stream>>>(E, Cc, fxn, fyn, out);
    }
}